// Round 13
// baseline (111.920 us; speedup 1.0000x reference)
//
#include <hip/hip_runtime.h>
#include <math.h>

// Problem shapes (fixed by setup_inputs)
#define BB 16
#define NN 16384
#define DD 256     // == O
#define NS1 128    // blocks per batch, pass 1 (xsum)
#define NS3 128    // blocks per batch, pass 2 (scores + flash partials)

typedef float floatx4 __attribute__((ext_vector_type(4)));

__device__ __forceinline__ floatx4 ntload4(const float* p) {
  return __builtin_nontemporal_load((const floatx4*)p);
}

// ---------------- K1: partial column-sums of x (round-12 proven form) -------
__global__ __launch_bounds__(256) void k1_xsum_part(const float* __restrict__ x,
                                                    float* __restrict__ part) {
  const int b = blockIdx.y, blk = blockIdx.x;
  const int wave = threadIdx.x >> 6, lane = threadIdx.x & 63;
  const int rows = NN / NS1;  // 128
  const float* xp = x + ((size_t)b * NN + (size_t)blk * rows + wave) * DD + lane * 4;
  floatx4 a0 = {0.f, 0.f, 0.f, 0.f}, a1 = a0, a2 = a0, a3 = a0;
  floatx4 a4 = a0, a5 = a0, a6 = a0, a7 = a0;
#pragma unroll
  for (int r = 0; r < rows; r += 32) {
    a0 += ntload4(xp + (size_t)(r + 0) * DD);
    a1 += ntload4(xp + (size_t)(r + 4) * DD);
    a2 += ntload4(xp + (size_t)(r + 8) * DD);
    a3 += ntload4(xp + (size_t)(r + 12) * DD);
    a4 += ntload4(xp + (size_t)(r + 16) * DD);
    a5 += ntload4(xp + (size_t)(r + 20) * DD);
    a6 += ntload4(xp + (size_t)(r + 24) * DD);
    a7 += ntload4(xp + (size_t)(r + 28) * DD);
  }
  const floatx4 acc = ((a0 + a1) + (a2 + a3)) + ((a4 + a5) + (a6 + a7));
  __shared__ float sP[4][DD];
  *(floatx4*)&sP[wave][lane * 4] = acc;
  __syncthreads();
  const int t = threadIdx.x;
  part[((size_t)b * NS1 + blk) * DD + t] = sP[0][t] + sP[1][t] + sP[2][t] + sP[3][t];
}

// ---------------- K2: part -> xsum -> ksum -> v, c (1024 threads) ----------
__global__ __launch_bounds__(1024) void k2_prep(const float* __restrict__ part,
                                                const float* __restrict__ Wq,
                                                const float* __restrict__ bq,
                                                const float* __restrict__ Wk,
                                                const float* __restrict__ bk,
                                                float* __restrict__ v,
                                                float* __restrict__ c) {
  const int b = blockIdx.x, t = threadIdx.x;
  const int d = t & 255;   // doubles as output index o
  const int g = t >> 8;    // 0..3
  __shared__ float stage[4][DD];
  __shared__ float xs[DD];
  __shared__ float ks[DD];
  __shared__ float red[256];

  const float* pb = part + (size_t)b * NS1 * DD + d;
  float a[8];
#pragma unroll
  for (int u = 0; u < 8; ++u) a[u] = 0.f;
#pragma unroll
  for (int blk = 0; blk < 32; blk += 8) {
#pragma unroll
    for (int u = 0; u < 8; ++u) a[u] += pb[(size_t)(g * 32 + blk + u) * DD];
  }
  stage[g][d] = ((a[0] + a[1]) + (a[2] + a[3])) + ((a[4] + a[5]) + (a[6] + a[7]));
  __syncthreads();
  if (g == 0) xs[d] = (stage[0][d] + stage[1][d]) + (stage[2][d] + stage[3][d]);
  __syncthreads();

  float kp = 0.f;
  const float4* wk4 = (const float4*)(Wk + (size_t)d * DD + g * 64);
#pragma unroll 4
  for (int j4 = 0; j4 < 16; ++j4) {
    const float4 w = wk4[j4];
    const int j = g * 64 + 4 * j4;
    kp += w.x * xs[j] + w.y * xs[j + 1] + w.z * xs[j + 2] + w.w * xs[j + 3];
  }
  stage[g][d] = kp;
  __syncthreads();
  if (g == 0)
    ks[d] = (stage[0][d] + stage[1][d]) + (stage[2][d] + stage[3][d]) + (float)NN * bk[d];
  __syncthreads();

  float vp = 0.f;
#pragma unroll 4
  for (int o = 0; o < 64; ++o)
    vp += Wq[(size_t)(g * 64 + o) * DD + d] * ks[g * 64 + o];
  stage[g][d] = vp;
  __syncthreads();
  if (g == 0) {
    v[b * DD + d] = (stage[0][d] + stage[1][d]) + (stage[2][d] + stage[3][d]);
    red[d] = bq[d] * ks[d];
  }
  __syncthreads();
  for (int s = 128; s > 0; s >>= 1) {
    if (t < s) red[t] += red[t + s];
    __syncthreads();
  }
  if (t == 0) c[b] = red[0];
}

// ---------------- K3: main pass — 32-lanes-per-row flash ----------------
// Lane l covers cols (l&31)*8..+7 of row n0+2p+(l>>5): one load-pair = 2 rows,
// butterfly = 5 shuffles / 2 rows, exp = 1 instr / 2 rows. Branchless update.
__global__ __launch_bounds__(256) void k3_main(const float* __restrict__ x,
                                               const float* __restrict__ v,
                                               const float* __restrict__ c,
                                               float* __restrict__ scores,
                                               float* __restrict__ pm,
                                               float* __restrict__ pz,
                                               float* __restrict__ pP) {
  const int b = blockIdx.y, blk = blockIdx.x;
  const int t = threadIdx.x;
  const int wave = t >> 6, lane = t & 63;
  const int hl = lane & 31;     // lane within half
  const int half = lane >> 5;   // 0 or 1
  const float scale = 0.0625f;  // 1/sqrt(256)

  const floatx4 vl0 = *(const floatx4*)(v + b * DD + hl * 8);
  const floatx4 vl1 = *(const floatx4*)(v + b * DD + hl * 8 + 4);
  const float cb = c[b];
  const int rows_per_block = NN / NS3;  // 128
  const int n0 = blk * rows_per_block + wave * 32;
  const float* xb = x + (size_t)b * NN * DD;

  float m = -INFINITY, Z = 0.f;
  floatx4 P0 = {0.f, 0.f, 0.f, 0.f};
  floatx4 P1 = {0.f, 0.f, 0.f, 0.f};

  for (int i = 0; i < 32; i += 8) {  // 4 row-pairs per iteration
    const float* rp0 = xb + (size_t)(n0 + i + 0 + half) * DD + hl * 8;
    const float* rp1 = xb + (size_t)(n0 + i + 2 + half) * DD + hl * 8;
    const float* rp2 = xb + (size_t)(n0 + i + 4 + half) * DD + hl * 8;
    const float* rp3 = xb + (size_t)(n0 + i + 6 + half) * DD + hl * 8;
    const floatx4 xa0 = ntload4(rp0), xc0 = ntload4(rp0 + 4);
    const floatx4 xa1 = ntload4(rp1), xc1 = ntload4(rp1 + 4);
    const floatx4 xa2 = ntload4(rp2), xc2 = ntload4(rp2 + 4);
    const floatx4 xa3 = ntload4(rp3), xc3 = ntload4(rp3 + 4);

#define DOT8(XA, XC) ({ const floatx4 _q0 = (XA) * vl0, _q1 = (XC) * vl1; \
                        ((_q0.x + _q0.y) + (_q0.z + _q0.w)) + \
                        ((_q1.x + _q1.y) + (_q1.z + _q1.w)); })
    float d0 = DOT8(xa0, xc0), d1 = DOT8(xa1, xc1);
    float d2 = DOT8(xa2, xc2), d3 = DOT8(xa3, xc3);
#undef DOT8
#pragma unroll
    for (int off = 16; off >= 1; off >>= 1) {  // 5-step butterfly within half
      d0 += __shfl_xor(d0, off, 64);
      d1 += __shfl_xor(d1, off, 64);
      d2 += __shfl_xor(d2, off, 64);
      d3 += __shfl_xor(d3, off, 64);
    }
    const float s0 = (d0 + cb) * scale, s1 = (d1 + cb) * scale;
    const float s2 = (d2 + cb) * scale, s3 = (d3 + cb) * scale;
    if (hl == 0) {  // lane 0 (rows i+2p) and lane 32 (rows i+2p+1)
      float* sc = scores + (size_t)b * NN + n0 + i + half;
      sc[0] = s0; sc[2] = s1; sc[4] = s2; sc[6] = s3;
    }
    // branchless online-softmax updates (per 32-lane half)
#define UPD(S, XA, XC) { \
    const float mn = fmaxf(m, (S)); \
    const float al = __expf(m - mn); \
    const float e  = __expf((S) - mn); \
    Z = Z * al + e; \
    P0 = P0 * al + (XA) * e; \
    P1 = P1 * al + (XC) * e; \
    m = mn; }
    UPD(s0, xa0, xc0)
    UPD(s1, xa1, xc1)
    UPD(s2, xa2, xc2)
    UPD(s3, xa3, xc3)
#undef UPD
  }

  // ---- combine the two halves of this wave ----
  const float mo = __shfl_xor(m, 32, 64);
  const float Mw = fmaxf(m, mo);
  const float eh = __expf(m - Mw);
  float Zp = Z * eh;
  Zp += __shfl_xor(Zp, 32, 64);
  floatx4 Q0 = P0 * eh, Q1 = P1 * eh;
  Q0.x += __shfl_xor(Q0.x, 32, 64); Q0.y += __shfl_xor(Q0.y, 32, 64);
  Q0.z += __shfl_xor(Q0.z, 32, 64); Q0.w += __shfl_xor(Q0.w, 32, 64);
  Q1.x += __shfl_xor(Q1.x, 32, 64); Q1.y += __shfl_xor(Q1.y, 32, 64);
  Q1.z += __shfl_xor(Q1.z, 32, 64); Q1.w += __shfl_xor(Q1.w, 32, 64);

  // ---- combine the 4 waves of this block ----
  __shared__ float sm[4], sz[4];
  __shared__ float sP[4][DD];
  if (half == 0) {
    *(floatx4*)&sP[wave][hl * 8] = Q0;
    *(floatx4*)&sP[wave][hl * 8 + 4] = Q1;
  }
  if (lane == 0) { sm[wave] = Mw; sz[wave] = Zp; }
  __syncthreads();

  const float M = fmaxf(fmaxf(sm[0], sm[1]), fmaxf(sm[2], sm[3]));
  const float e0 = __expf(sm[0] - M), e1 = __expf(sm[1] - M);
  const float e2 = __expf(sm[2] - M), e3 = __expf(sm[3] - M);
  const float Pd = sP[0][t] * e0 + sP[1][t] * e1 + sP[2][t] * e2 + sP[3][t] * e3;
  const size_t idx = (size_t)b * NS3 + blk;
  pP[idx * DD + t] = Pd;
  if (t == 0) {
    pm[idx] = M;
    pz[idx] = sz[0] * e0 + sz[1] * e1 + sz[2] * e2 + sz[3] * e3;
  }
}

// ---------------- K45: merged finalization (round-12 form) ----------------
__global__ __launch_bounds__(256) void k45_final(const float* __restrict__ pm,
                                                 const float* __restrict__ pz,
                                                 const float* __restrict__ pP,
                                                 const float* __restrict__ scores,
                                                 float* __restrict__ out_agg,
                                                 float* __restrict__ out_w) {
  const int t = threadIdx.x;
  if (blockIdx.x < BB) {
    const int b = blockIdx.x;
    __shared__ float red[256];
    __shared__ float sw[NS3];
    const size_t base = (size_t)b * NS3;

    red[t] = (t < NS3) ? pm[base + t] : -INFINITY;
    __syncthreads();
    for (int s = 128; s > 0; s >>= 1) {
      if (t < s) red[t] = fmaxf(red[t], red[t + s]);
      __syncthreads();
    }
    const float M = red[0];
    __syncthreads();

    const float w_t = (t < NS3) ? __expf(pm[base + t] - M) : 0.f;
    if (t < NS3) sw[t] = w_t;
    red[t] = (t < NS3) ? pz[base + t] * w_t : 0.f;
    __syncthreads();
    for (int s = 128; s > 0; s >>= 1) {
      if (t < s) red[t] += red[t + s];
      __syncthreads();
    }
    const float rZ = 1.f / red[0];

    float a0 = 0.f, a1 = 0.f, a2 = 0.f, a3 = 0.f;
    const float* pb = pP + base * DD + t;
#pragma unroll 8
    for (int blk = 0; blk < NS3; blk += 4) {
      a0 += pb[(size_t)(blk + 0) * DD] * sw[blk + 0];
      a1 += pb[(size_t)(blk + 1) * DD] * sw[blk + 1];
      a2 += pb[(size_t)(blk + 2) * DD] * sw[blk + 2];
      a3 += pb[(size_t)(blk + 3) * DD] * sw[blk + 3];
    }
    out_agg[b * DD + t] = ((a0 + a1) + (a2 + a3)) * rZ;
  } else {
    const int wb = blockIdx.x - BB;
    __shared__ float sM[BB], sR[BB];
    const int b = t >> 4;
    const int i = t & 15;
    const size_t base = (size_t)b * NS3 + i * 8;

    float mloc = -INFINITY;
#pragma unroll
    for (int k = 0; k < 8; ++k) mloc = fmaxf(mloc, pm[base + k]);
#pragma unroll
    for (int off = 8; off >= 1; off >>= 1) mloc = fmaxf(mloc, __shfl_xor(mloc, off, 64));
    const float M = mloc;

    float zloc = 0.f;
#pragma unroll
    for (int k = 0; k < 8; ++k) zloc += pz[base + k] * __expf(pm[base + k] - M);
#pragma unroll
    for (int off = 8; off >= 1; off >>= 1) zloc += __shfl_xor(zloc, off, 64);

    if (i == 0) { sM[b] = M; sR[b] = 1.f / zloc; }
    __syncthreads();

    const int n = wb * 256 + t;
    float acc = 0.f;
#pragma unroll
    for (int bb = 0; bb < BB; ++bb)
      acc += __expf(scores[(size_t)bb * NN + n] - sM[bb]) * sR[bb];
    out_w[n] = acc * (1.f / BB);
  }
}

extern "C" void kernel_launch(void* const* d_in, const int* in_sizes, int n_in,
                              void* d_out, int out_size, void* d_ws, size_t ws_size,
                              hipStream_t stream) {
  const float* x  = (const float*)d_in[0];
  const float* Wq = (const float*)d_in[1];
  const float* bq = (const float*)d_in[2];
  const float* Wk = (const float*)d_in[3];
  const float* bk = (const float*)d_in[4];

  float* out  = (float*)d_out;
  float* agg  = out;             // [16, 256]
  float* avgw = out + BB * DD;   // [16384]

  float* ws = (float*)d_ws;
  float* part   = ws;  ws += (size_t)BB * NS1 * DD;  // 524288
  float* v      = ws;  ws += BB * DD;                // 4096
  float* c      = ws;  ws += BB;                     // 16
  float* scores = ws;  ws += (size_t)BB * NN;        // 262144
  float* pm     = ws;  ws += BB * NS3;               // 2048
  float* pz     = ws;  ws += BB * NS3;               // 2048
  float* pP     = ws;  ws += (size_t)BB * NS3 * DD;  // 524288

  k1_xsum_part<<<dim3(NS1, BB), 256, 0, stream>>>(x, part);
  k2_prep<<<BB, 1024, 0, stream>>>(part, Wq, bq, Wk, bk, v, c);
  k3_main<<<dim3(NS3, BB), 256, 0, stream>>>(x, v, c, scores, pm, pz, pP);
  k45_final<<<BB + NN / 256, 256, 0, stream>>>(pm, pz, pP, scores, agg, avgw);
}

// Round 14
// 108.764 us; speedup vs baseline: 1.0290x; 1.0290x over previous
//
#include <hip/hip_runtime.h>
#include <math.h>

// Problem shapes (fixed by setup_inputs)
#define BB 16
#define NN 16384
#define DD 256     // == O
#define NS1 128    // blocks per batch, pass 1 (xsum)
#define NS3 128    // blocks per batch, pass 2 (scores + flash partials)

typedef float floatx4 __attribute__((ext_vector_type(4)));

__device__ __forceinline__ floatx4 ntload4(const float* p) {
  return __builtin_nontemporal_load((const floatx4*)p);
}

// ---------------- K1: partial column-sums of x ----------------
// grid (NS1, BB), block 256 (4 waves). Wave w takes rows w, w+4, ... (proven
// traversal) — 8 independent accumulators => 8 NT loads in flight per wave.
__global__ __launch_bounds__(256) void k1_xsum_part(const float* __restrict__ x,
                                                    float* __restrict__ part) {
  const int b = blockIdx.y, blk = blockIdx.x;
  const int wave = threadIdx.x >> 6, lane = threadIdx.x & 63;
  const int rows = NN / NS1;  // 128
  const float* xp = x + ((size_t)b * NN + (size_t)blk * rows + wave) * DD + lane * 4;
  floatx4 a0 = {0.f, 0.f, 0.f, 0.f}, a1 = a0, a2 = a0, a3 = a0;
  floatx4 a4 = a0, a5 = a0, a6 = a0, a7 = a0;
#pragma unroll
  for (int r = 0; r < rows; r += 32) {  // wave's rows: wave + {0,4,...,28} + 32k
    a0 += ntload4(xp + (size_t)(r + 0) * DD);
    a1 += ntload4(xp + (size_t)(r + 4) * DD);
    a2 += ntload4(xp + (size_t)(r + 8) * DD);
    a3 += ntload4(xp + (size_t)(r + 12) * DD);
    a4 += ntload4(xp + (size_t)(r + 16) * DD);
    a5 += ntload4(xp + (size_t)(r + 20) * DD);
    a6 += ntload4(xp + (size_t)(r + 24) * DD);
    a7 += ntload4(xp + (size_t)(r + 28) * DD);
  }
  const floatx4 acc = ((a0 + a1) + (a2 + a3)) + ((a4 + a5) + (a6 + a7));
  __shared__ float sP[4][DD];
  *(floatx4*)&sP[wave][lane * 4] = acc;
  __syncthreads();
  const int t = threadIdx.x;
  part[((size_t)b * NS1 + blk) * DD + t] = sP[0][t] + sP[1][t] + sP[2][t] + sP[3][t];
}

// ---------------- K2: part -> xsum -> ksum -> v, c (1024 threads) ----------
__global__ __launch_bounds__(1024) void k2_prep(const float* __restrict__ part,
                                                const float* __restrict__ Wq,
                                                const float* __restrict__ bq,
                                                const float* __restrict__ Wk,
                                                const float* __restrict__ bk,
                                                float* __restrict__ v,
                                                float* __restrict__ c) {
  const int b = blockIdx.x, t = threadIdx.x;
  const int d = t & 255;   // doubles as output index o
  const int g = t >> 8;    // 0..3
  __shared__ float stage[4][DD];
  __shared__ float xs[DD];
  __shared__ float ks[DD];
  __shared__ float red[256];

  // ---- part walk: tiles [g*32, g*32+32), 8 accumulators ----
  const float* pb = part + (size_t)b * NS1 * DD + d;
  float a[8];
#pragma unroll
  for (int u = 0; u < 8; ++u) a[u] = 0.f;
#pragma unroll
  for (int blk = 0; blk < 32; blk += 8) {
#pragma unroll
    for (int u = 0; u < 8; ++u) a[u] += pb[(size_t)(g * 32 + blk + u) * DD];
  }
  stage[g][d] = ((a[0] + a[1]) + (a[2] + a[3])) + ((a[4] + a[5]) + (a[6] + a[7]));
  __syncthreads();
  if (g == 0) xs[d] = (stage[0][d] + stage[1][d]) + (stage[2][d] + stage[3][d]);
  __syncthreads();

  // ---- ksum[o] partials: group g covers j in [g*64, g*64+64) ----
  float kp = 0.f;
  const float4* wk4 = (const float4*)(Wk + (size_t)d * DD + g * 64);
#pragma unroll 4
  for (int j4 = 0; j4 < 16; ++j4) {
    const float4 w = wk4[j4];
    const int j = g * 64 + 4 * j4;
    kp += w.x * xs[j] + w.y * xs[j + 1] + w.z * xs[j + 2] + w.w * xs[j + 3];
  }
  stage[g][d] = kp;
  __syncthreads();
  if (g == 0)
    ks[d] = (stage[0][d] + stage[1][d]) + (stage[2][d] + stage[3][d]) + (float)NN * bk[d];
  __syncthreads();

  // ---- v[d] partials: group g covers o in [g*64, g*64+64) ----
  float vp = 0.f;
#pragma unroll 4
  for (int o = 0; o < 64; ++o)
    vp += Wq[(size_t)(g * 64 + o) * DD + d] * ks[g * 64 + o];
  stage[g][d] = vp;
  __syncthreads();
  if (g == 0) {
    v[b * DD + d] = (stage[0][d] + stage[1][d]) + (stage[2][d] + stage[3][d]);
    red[d] = bq[d] * ks[d];
  }
  __syncthreads();
  for (int s = 128; s > 0; s >>= 1) {
    if (t < s) red[t] += red[t + s];
    __syncthreads();
  }
  if (t == 0) c[b] = red[0];
}

// ---------------- K3: main pass — 8-row batched flash ----------------
__global__ __launch_bounds__(256) void k3_main(const float* __restrict__ x,
                                               const float* __restrict__ v,
                                               const float* __restrict__ c,
                                               float* __restrict__ scores,
                                               float* __restrict__ pm,
                                               float* __restrict__ pz,
                                               float* __restrict__ pP) {
  const int b = blockIdx.y, blk = blockIdx.x;
  const int wave = threadIdx.x >> 6, lane = threadIdx.x & 63;
  const float scale = 0.0625f;  // 1/sqrt(256)

  const floatx4 vl = *(const floatx4*)(v + b * DD + lane * 4);
  const float cb = c[b];
  const int rows_per_block = NN / NS3;          // 128
  const int rows_per_wave = rows_per_block / 4; // 32
  const int n0 = blk * rows_per_block + wave * rows_per_wave;
  const float* xb = x + (size_t)b * NN * DD;

  float m = -INFINITY, Z = 0.f;
  floatx4 P = {0.f, 0.f, 0.f, 0.f};

#define DOT_OF(XR) ({ const floatx4 _p = (XR) * vl; _p.x + _p.y + _p.z + _p.w; })

  for (int i = 0; i < rows_per_wave; i += 8) {
    const float* base = xb + (size_t)(n0 + i) * DD + lane * 4;
    const floatx4 xr0 = ntload4(base);
    const floatx4 xr1 = ntload4(base + DD);
    const floatx4 xr2 = ntload4(base + 2 * DD);
    const floatx4 xr3 = ntload4(base + 3 * DD);
    const floatx4 xr4 = ntload4(base + 4 * DD);
    const floatx4 xr5 = ntload4(base + 5 * DD);
    const floatx4 xr6 = ntload4(base + 6 * DD);
    const floatx4 xr7 = ntload4(base + 7 * DD);
    float d0 = DOT_OF(xr0), d1 = DOT_OF(xr1), d2 = DOT_OF(xr2), d3 = DOT_OF(xr3);
    float d4 = DOT_OF(xr4), d5 = DOT_OF(xr5), d6 = DOT_OF(xr6), d7 = DOT_OF(xr7);
#pragma unroll
    for (int off = 32; off >= 1; off >>= 1) {  // 8 independent butterfly chains
      d0 += __shfl_xor(d0, off, 64);
      d1 += __shfl_xor(d1, off, 64);
      d2 += __shfl_xor(d2, off, 64);
      d3 += __shfl_xor(d3, off, 64);
      d4 += __shfl_xor(d4, off, 64);
      d5 += __shfl_xor(d5, off, 64);
      d6 += __shfl_xor(d6, off, 64);
      d7 += __shfl_xor(d7, off, 64);
    }
    const float s0 = (d0 + cb) * scale, s1 = (d1 + cb) * scale;
    const float s2 = (d2 + cb) * scale, s3 = (d3 + cb) * scale;
    const float s4 = (d4 + cb) * scale, s5 = (d5 + cb) * scale;
    const float s6 = (d6 + cb) * scale, s7 = (d7 + cb) * scale;
    if (lane == 0) {
      floatx4 sva = {s0, s1, s2, s3};
      floatx4 svb = {s4, s5, s6, s7};
      *(floatx4*)(scores + (size_t)b * NN + n0 + i) = sva;
      *(floatx4*)(scores + (size_t)b * NN + n0 + i + 4) = svb;
    }
    // sequential online-softmax updates (wave-uniform branches)
#define SM_UPDATE(S, XR)                                   \
    if ((S) > m) {                                         \
      const float alpha = __expf(m - (S));                 \
      Z = Z * alpha + 1.f;                                 \
      P = P * alpha + (XR);                                \
      m = (S);                                             \
    } else {                                               \
      const float e = __expf((S) - m);                     \
      Z += e;                                              \
      P += (XR) * e;                                       \
    }
    SM_UPDATE(s0, xr0)
    SM_UPDATE(s1, xr1)
    SM_UPDATE(s2, xr2)
    SM_UPDATE(s3, xr3)
    SM_UPDATE(s4, xr4)
    SM_UPDATE(s5, xr5)
    SM_UPDATE(s6, xr6)
    SM_UPDATE(s7, xr7)
#undef SM_UPDATE
  }

  // combine the 4 waves of this block
  __shared__ float sm[4], sz[4];
  __shared__ float sP[4][DD];
  *(floatx4*)&sP[wave][lane * 4] = P;
  if (lane == 0) { sm[wave] = m; sz[wave] = Z; }
  __syncthreads();

  const int t = threadIdx.x;
  const float M = fmaxf(fmaxf(sm[0], sm[1]), fmaxf(sm[2], sm[3]));
  const float e0 = __expf(sm[0] - M), e1 = __expf(sm[1] - M);
  const float e2 = __expf(sm[2] - M), e3 = __expf(sm[3] - M);
  const float Pd = sP[0][t] * e0 + sP[1][t] * e1 + sP[2][t] * e2 + sP[3][t] * e3;
  const size_t idx = (size_t)b * NS3 + blk;
  pP[idx * DD + t] = Pd;
  if (t == 0) {
    pm[idx] = M;
    pz[idx] = sz[0] * e0 + sz[1] * e1 + sz[2] * e2 + sz[3] * e3;
  }
}

// ---------------- K45: merged finalization ----------------
__global__ __launch_bounds__(256) void k45_final(const float* __restrict__ pm,
                                                 const float* __restrict__ pz,
                                                 const float* __restrict__ pP,
                                                 const float* __restrict__ scores,
                                                 float* __restrict__ out_agg,
                                                 float* __restrict__ out_w) {
  const int t = threadIdx.x;
  if (blockIdx.x < BB) {
    // ---- role A: aggregated_feature[b] ----
    const int b = blockIdx.x;
    __shared__ float red[256];
    __shared__ float sw[NS3];
    const size_t base = (size_t)b * NS3;

    red[t] = (t < NS3) ? pm[base + t] : -INFINITY;
    __syncthreads();
    for (int s = 128; s > 0; s >>= 1) {
      if (t < s) red[t] = fmaxf(red[t], red[t + s]);
      __syncthreads();
    }
    const float M = red[0];
    __syncthreads();

    const float w_t = (t < NS3) ? __expf(pm[base + t] - M) : 0.f;
    if (t < NS3) sw[t] = w_t;
    red[t] = (t < NS3) ? pz[base + t] * w_t : 0.f;
    __syncthreads();
    for (int s = 128; s > 0; s >>= 1) {
      if (t < s) red[t] += red[t + s];
      __syncthreads();
    }
    const float rZ = 1.f / red[0];

    // 4-accumulator unroll of the 128-tile pP walk
    float a0 = 0.f, a1 = 0.f, a2 = 0.f, a3 = 0.f;
    const float* pb = pP + base * DD + t;
#pragma unroll 8
    for (int blk = 0; blk < NS3; blk += 4) {
      a0 += pb[(size_t)(blk + 0) * DD] * sw[blk + 0];
      a1 += pb[(size_t)(blk + 1) * DD] * sw[blk + 1];
      a2 += pb[(size_t)(blk + 2) * DD] * sw[blk + 2];
      a3 += pb[(size_t)(blk + 3) * DD] * sw[blk + 3];
    }
    out_agg[b * DD + t] = ((a0 + a1) + (a2 + a3)) * rZ;
  } else {
    // ---- role B: average_customer_weights ----
    const int wb = blockIdx.x - BB;
    __shared__ float sM[BB], sR[BB];
    const int b = t >> 4;
    const int i = t & 15;
    const size_t base = (size_t)b * NS3 + i * 8;

    float mloc = -INFINITY;
#pragma unroll
    for (int k = 0; k < 8; ++k) mloc = fmaxf(mloc, pm[base + k]);
#pragma unroll
    for (int off = 8; off >= 1; off >>= 1) mloc = fmaxf(mloc, __shfl_xor(mloc, off, 64));
    const float M = mloc;

    float zloc = 0.f;
#pragma unroll
    for (int k = 0; k < 8; ++k) zloc += pz[base + k] * __expf(pm[base + k] - M);
#pragma unroll
    for (int off = 8; off >= 1; off >>= 1) zloc += __shfl_xor(zloc, off, 64);

    if (i == 0) { sM[b] = M; sR[b] = 1.f / zloc; }
    __syncthreads();

    const int n = wb * 256 + t;
    float acc = 0.f;
#pragma unroll
    for (int bb = 0; bb < BB; ++bb)
      acc += __expf(scores[(size_t)bb * NN + n] - sM[bb]) * sR[bb];
    out_w[n] = acc * (1.f / BB);
  }
}

extern "C" void kernel_launch(void* const* d_in, const int* in_sizes, int n_in,
                              void* d_out, int out_size, void* d_ws, size_t ws_size,
                              hipStream_t stream) {
  const float* x  = (const float*)d_in[0];
  const float* Wq = (const float*)d_in[1];
  const float* bq = (const float*)d_in[2];
  const float* Wk = (const float*)d_in[3];
  const float* bk = (const float*)d_in[4];

  float* out  = (float*)d_out;
  float* agg  = out;             // [16, 256]
  float* avgw = out + BB * DD;   // [16384]

  float* ws = (float*)d_ws;
  float* part   = ws;  ws += (size_t)BB * NS1 * DD;  // 524288
  float* v      = ws;  ws += BB * DD;                // 4096
  float* c      = ws;  ws += BB;                     // 16
  float* scores = ws;  ws += (size_t)BB * NN;        // 262144
  float* pm     = ws;  ws += BB * NS3;               // 2048
  float* pz     = ws;  ws += BB * NS3;               // 2048
  float* pP     = ws;  ws += (size_t)BB * NS3 * DD;  // 524288

  k1_xsum_part<<<dim3(NS1, BB), 256, 0, stream>>>(x, part);
  k2_prep<<<BB, 1024, 0, stream>>>(part, Wq, bq, Wk, bk, v, c);
  k3_main<<<dim3(NS3, BB), 256, 0, stream>>>(x, v, c, scores, pm, pz, pP);
  k45_final<<<BB + NN / 256, 256, 0, stream>>>(pm, pz, pP, scores, agg, avgw);
}